// Round 4
// baseline (428.577 us; speedup 1.0000x reference)
//
#include <hip/hip_runtime.h>
#include <math.h>

// Octonion product via Cayley-Dickson over quaternions (matches reference's
// _oct_structure exactly).
__device__ __forceinline__ void qmul(float w1, float x1, float y1, float z1,
                                     float w2, float x2, float y2, float z2,
                                     float& w, float& x, float& y, float& z) {
    w = w1 * w2 - x1 * x2 - y1 * y2 - z1 * z2;
    x = w1 * x2 + x1 * w2 + y1 * z2 - z1 * y2;
    y = w1 * y2 - x1 * z2 + y1 * w2 + z1 * x2;
    z = w1 * z2 + x1 * y2 - y1 * x2 + z1 * w2;
}

// Persistent-wave software pipeline, NO __syncthreads:
//  - each 64-lane wave owns a private 14 KiB LDS slice (4 waves/block = 56 KiB)
//  - per tile (64 batches): scatter prefetched regs -> LDS (swizzled, conflict-free),
//    issue next tile's 14 coalesced float4 loads, then LDS read-back + compute.
//  - intra-wave DS ops are HW-ordered; global loads for tile k+1 stay in flight
//    across the whole compute of tile k (the r2/r3 barrier serialized these).
__global__ __launch_bounds__(256) void oct_fano_kernel(
    const float* __restrict__ in,    // (B, 7, 8) fp32
    const float* __restrict__ logs,  // scalar log_sensitivity
    float* __restrict__ out,         // (B,) fp32
    int B, int ntiles) {
    __shared__ __align__(16) float4 lds4[4 * 14 * 64];  // 56 KiB, 14 KiB per wave

    const int t = threadIdx.x & 63;          // lane
    const int w = threadIdx.x >> 6;          // wave within block
    float4* __restrict__ L = &lds4[w * (14 * 64)];

    const int wstride = gridDim.x * 4;       // total persistent waves
    int tile = blockIdx.x * 4 + w;
    const float sens = expf(logs[0]);

    float4 v[14];
    // ---- prologue: load first tile (coalesced: lane-contiguous float4) ----
    if (tile < ntiles) {
        const float4* gp = (const float4*)in + (size_t)tile * 896;
        int nch = min(64, B - (tile << 6)) * 14;
#pragma unroll
        for (int i = 0; i < 14; i++) {
            int g = i * 64 + t;
            if (g < nch) v[i] = gp[g];
        }
    }

    while (tile < ntiles) {
        const int nb = min(64, B - (tile << 6));
        const int nch = nb * 14;

        // ---- staged regs -> wave-private LDS (swizzled scatter) ----
#pragma unroll
        for (int i = 0; i < 14; i++) {
            int g = i * 64 + t;
            if (g < nch) {
                int bg = g / 14;           // magic-mul
                int cg = g - bg * 14;
                L[cg * 64 + ((bg + cg) & 63)] = v[i];
            }
        }

        // ---- issue NEXT tile's loads now; they fly during compute below ----
        const int next = tile + wstride;
        if (next < ntiles) {
            const float4* gp = (const float4*)in + (size_t)next * 896;
            int nch2 = min(64, B - (next << 6)) * 14;
#pragma unroll
            for (int i = 0; i < 14; i++) {
                int g = i * 64 + t;
                if (g < nch2) v[i] = gp[g];
            }
        }

        // ---- compute this wave's 64 batches from LDS ----
        if (t < nb) {
            float x[7][8];
#pragma unroll
            for (int k = 0; k < 14; k++) {
                float4 q = L[k * 64 + ((t + k) & 63)];
                int r = k >> 1;
                int c = (k & 1) * 4;
                x[r][c + 0] = q.x;
                x[r][c + 1] = q.y;
                x[r][c + 2] = q.z;
                x[r][c + 3] = q.w;
            }

            // normalize rows
#pragma unroll
            for (int r = 0; r < 7; r++) {
                float s = 0.f;
#pragma unroll
                for (int c = 0; c < 8; c++) s += x[r][c] * x[r][c];
                float n = fmaxf(sqrtf(s), 1e-12f);
                float inv = 1.0f / n;
#pragma unroll
                for (int c = 0; c < 8; c++) x[r][c] *= inv;
            }

            // 7 Fano lines: (i, j, k) = (l, (l+1)%7, (l+3)%7)
            float total = 0.f;
#pragma unroll
            for (int l = 0; l < 7; l++) {
                const float* a = x[l];
                const float* bb = x[(l + 1) % 7];
                const float* ck = x[(l + 3) % 7];

                float p0, p1, p2, p3, p4, p5, p6, p7;
                float t0, t1, t2, t3;
                qmul(a[0], a[1], a[2], a[3], bb[0], bb[1], bb[2], bb[3], p0, p1, p2, p3);
                qmul(bb[4], -bb[5], -bb[6], -bb[7], a[4], a[5], a[6], a[7], t0, t1, t2, t3);
                p0 -= t0; p1 -= t1; p2 -= t2; p3 -= t3;
                qmul(bb[4], bb[5], bb[6], bb[7], a[0], a[1], a[2], a[3], p4, p5, p6, p7);
                qmul(a[4], a[5], a[6], a[7], bb[0], -bb[1], -bb[2], -bb[3], t0, t1, t2, t3);
                p4 += t0; p5 += t1; p6 += t2; p7 += t3;

                float d0 = p0 - ck[0], d1 = p1 - ck[1], d2 = p2 - ck[2], d3 = p3 - ck[3];
                float d4 = p4 - ck[4], d5 = p5 - ck[5], d6 = p6 - ck[6], d7 = p7 - ck[7];
                total += d0 * d0 + d1 * d1 + d2 * d2 + d3 * d3 +
                         d4 * d4 + d5 * d5 + d6 * d6 + d7 * d7;
            }

            float avg = total * (1.0f / 7.0f);
            float phi = -logf(avg + 1e-8f) * sens;
            phi = fminf(fmaxf(phi, 0.0f), 10.0f);
            out[(tile << 6) + t] = phi;
        }

        tile = next;
    }
}

extern "C" void kernel_launch(void* const* d_in, const int* in_sizes, int n_in,
                              void* d_out, int out_size, void* d_ws, size_t ws_size,
                              hipStream_t stream) {
    const float* states = (const float*)d_in[0];
    const float* logs = (const float*)d_in[1];
    float* out = (float*)d_out;
    int B = in_sizes[0] / 56;            // 7*8 floats per batch
    int ntiles = (B + 63) / 64;          // 64 batches per wave-tile
    int nblocks = (ntiles + 3) / 4;
    if (nblocks > 512) nblocks = 512;    // 2 blocks/CU x 256 CUs, persistent
    oct_fano_kernel<<<nblocks, 256, 0, stream>>>(states, logs, out, B, ntiles);
}

// Round 5
// 313.446 us; speedup vs baseline: 1.3673x; 1.3673x over previous
//
#include <hip/hip_runtime.h>
#include <math.h>
#include <stdint.h>

// Octonion product via Cayley-Dickson over quaternions (matches reference's
// _oct_structure exactly).
__device__ __forceinline__ void qmul(float w1, float x1, float y1, float z1,
                                     float w2, float x2, float y2, float z2,
                                     float& w, float& x, float& y, float& z) {
    w = w1 * w2 - x1 * x2 - y1 * y2 - z1 * z2;
    x = w1 * x2 + x1 * w2 + y1 * z2 - z1 * y2;
    y = w1 * y2 - x1 * z2 + y1 * w2 + z1 * x2;
    z = w1 * z2 + x1 * y2 - y1 * x2 + z1 * w2;
}

typedef __attribute__((address_space(3))) uint32_t lds_u32;
typedef const __attribute__((address_space(1))) uint32_t glb_u32;

// One wave (64 threads) per 64-batch tile. Staging via global_load_lds
// width=16: HBM -> LDS DMA with ZERO staging VGPRs (round-4's v[14] register
// prefetch spilled 235 MB of scratch to HBM -- that was the killer).
// 14 KiB LDS/block -> ~11 blocks/CU; independent waves in different
// load/compute phases keep HBM saturated (m114-style overlap), no barriers.
__global__ __launch_bounds__(64) void oct_fano_kernel(
    const float* __restrict__ in,    // (B, 7, 8) fp32
    const float* __restrict__ logs,  // scalar log_sensitivity
    float* __restrict__ out,         // (B,) fp32
    int B) {
    __shared__ __align__(16) float4 lds4[14 * 64];  // 14 KiB, linear AoS image

    const int t = threadIdx.x;           // lane
    const int tile = blockIdx.x;
    const int nb = min(64, B - (tile << 6));

    // ---- HBM -> LDS direct DMA: 14 x (64 lanes x 16B) = 14 KiB ----
    // Lane-contiguous float4 addresses per instruction (1 KiB window = 8 cache
    // lines, fully coalesced). LDS dst = uniform base + lane*16 (HW rule).
    const float4* gp = (const float4*)in;
    const long gbase = (long)tile * 896;         // first float4 granule of tile
    const long gmax = (long)B * 14 - 1;          // clamp for tail tile
#pragma unroll
    for (int c = 0; c < 14; c++) {
        long idx = gbase + c * 64 + t;
        if (idx > gmax) idx = gmax;              // duplicate-load, harmless
        __builtin_amdgcn_global_load_lds((glb_u32*)(gp + idx),
                                         (lds_u32*)&lds4[c * 64], 16, 0, 0);
    }
    // wait all DMA done: vmcnt(0), lgkmcnt=15(nowait), expcnt=7(nowait)
    __builtin_amdgcn_s_waitcnt(0x0F70);
    __builtin_amdgcn_sched_barrier(0);           // keep ds_reads after the wait

    if (t < nb) {
        // ---- per-thread readback: batch t at float4 index t*14 ----
        float x[7][8];
#pragma unroll
        for (int k = 0; k < 14; k++) {
            float4 q = lds4[t * 14 + k];
            int r = k >> 1;
            int c = (k & 1) * 4;
            x[r][c + 0] = q.x;
            x[r][c + 1] = q.y;
            x[r][c + 2] = q.z;
            x[r][c + 3] = q.w;
        }

        // normalize rows: norm = max(||x||, 1e-12)
#pragma unroll
        for (int r = 0; r < 7; r++) {
            float s = 0.f;
#pragma unroll
            for (int c = 0; c < 8; c++) s += x[r][c] * x[r][c];
            float n = fmaxf(sqrtf(s), 1e-12f);
            float inv = 1.0f / n;
#pragma unroll
            for (int c = 0; c < 8; c++) x[r][c] *= inv;
        }

        // 7 Fano lines: (i, j, k) = (l, (l+1)%7, (l+3)%7)
        float total = 0.f;
#pragma unroll
        for (int l = 0; l < 7; l++) {
            const float* a = x[l];
            const float* bb = x[(l + 1) % 7];
            const float* ck = x[(l + 3) % 7];

            float p0, p1, p2, p3, p4, p5, p6, p7;
            float t0, t1, t2, t3;
            // c1 = qmul(a1, b1) - qmul(conj(b2), a2)
            qmul(a[0], a[1], a[2], a[3], bb[0], bb[1], bb[2], bb[3], p0, p1, p2, p3);
            qmul(bb[4], -bb[5], -bb[6], -bb[7], a[4], a[5], a[6], a[7], t0, t1, t2, t3);
            p0 -= t0; p1 -= t1; p2 -= t2; p3 -= t3;
            // c2 = qmul(b2, a1) + qmul(a2, conj(b1))
            qmul(bb[4], bb[5], bb[6], bb[7], a[0], a[1], a[2], a[3], p4, p5, p6, p7);
            qmul(a[4], a[5], a[6], a[7], bb[0], -bb[1], -bb[2], -bb[3], t0, t1, t2, t3);
            p4 += t0; p5 += t1; p6 += t2; p7 += t3;

            float d0 = p0 - ck[0], d1 = p1 - ck[1], d2 = p2 - ck[2], d3 = p3 - ck[3];
            float d4 = p4 - ck[4], d5 = p5 - ck[5], d6 = p6 - ck[6], d7 = p7 - ck[7];
            total += d0 * d0 + d1 * d1 + d2 * d2 + d3 * d3 +
                     d4 * d4 + d5 * d5 + d6 * d6 + d7 * d7;
        }

        float avg = total * (1.0f / 7.0f);
        float phi = -logf(avg + 1e-8f) * expf(logs[0]);
        phi = fminf(fmaxf(phi, 0.0f), 10.0f);
        out[(tile << 6) + t] = phi;
    }
}

extern "C" void kernel_launch(void* const* d_in, const int* in_sizes, int n_in,
                              void* d_out, int out_size, void* d_ws, size_t ws_size,
                              hipStream_t stream) {
    const float* states = (const float*)d_in[0];
    const float* logs = (const float*)d_in[1];
    float* out = (float*)d_out;
    int B = in_sizes[0] / 56;            // 7*8 floats per batch
    int ntiles = (B + 63) / 64;          // one wave-block per 64-batch tile
    oct_fano_kernel<<<ntiles, 64, 0, stream>>>(states, logs, out, B);
}